// Round 6
// baseline (112.399 us; speedup 1.0000x reference)
//
#include <hip/hip_runtime.h>
#include <math.h>

// ---------------- problem constants ----------------
#define SRATE   44100
#define T_IN    441000
#define BATCH   8
#define NB      3
#define NSEQ    (NB*BATCH)        // 24
#define TB_OUT  160000
#define NEW_R   160
#define ORIG_R  441
#define KW      475               // sinc taps
#define KP      480               // K padded to 15*32 for MFMA
#define WIDTH   17
#define NFRAMES 1000

// IIR chunking: 441000 = 2625 * 168 ; warmup 120 (pole 0.9357 -> e^-7.97 = 3.4e-4 residual,
// R5 proved 2.1e-4 is at the bf16 comparison floor; span 288 = 18 exact 16-sample groups)
#define LCHUNK  168
#define NCHUNK  2625
#define WARM    120

// merged scan+init grid split: scan blocks first (long pole), kt-init blocks appended
#define SCAN_BLOCKS 247           // ceil(63000/256)
#define KT_BLOCKS   300           // 76800/256 exact

// workspace layout
#define KTH_OFF 0                 // frag-major bf16 table: 160*480 ushort = 153.6 KB
#define XLP_OFF (1u<<20)          // xlp bf16: 24*441000*2 = 21.2 MB (L2-resident)

typedef __attribute__((ext_vector_type(4))) float floatx4;
typedef __attribute__((ext_vector_type(8))) short short8;

// bf16 RNE (manual, used in kt-init where exact XLA-style RNE is cheap & off hot path)
__device__ inline unsigned short f2bf(float f) {
    union { float f; unsigned u; } v; v.f = f;
    unsigned u = v.u, r = (u >> 16) & 0xffffu, rem = u & 0xffffu;
    if (rem > 0x8000u || (rem == 0x8000u && (r & 1u))) r++;
    return (unsigned short)r;
}

// frag-major flat index for the GLOBAL B-table:
// element ktT[p][k] with p = pblk*16+n, k = ks*32 + qd*8 + j
// -> flat = pblk*7680 + ks*512 + (qd*16+n)*8 + j  (wave load = contiguous 1KB)
__device__ inline int fragB(int p, int k) {
    int pblk = p >> 4, n = p & 15;
    int ks = k >> 5, qd = (k >> 3) & 3, j = k & 7;
    return pblk * 7680 + ks * 512 + (qd * 16 + n) * 8 + j;
}

// ---------------- fused scan + sinc-table-init (merged launch) ----------------
// Heterodyne = XLA-f32 arithmetic (validated R5-R7 at bf16 floor) — numerics bit-identical.
// xlp is stored as bf16 (hw v_cvt_pk RNE): quantization commutes with the copy — the
// resample staged exactly these bf16 values in R5, so outputs are BIT-IDENTICAL while
// halving scan write traffic (42.3 -> 21.2 MB) and making resample reads L2-resident.
struct ScanParams {
    float b0[NB], a1[NB], a2[NB], w[NB];
    float lb0, lb1, lb2, la1, la2;
};

__global__ __launch_bounds__(256) void scan_init_kernel(const float* __restrict__ x,
                                                        unsigned short* __restrict__ xlp,
                                                        unsigned short* __restrict__ kth,
                                                        ScanParams P) {
    if (blockIdx.x >= SCAN_BLOCKS) {
        // ---- kt_init branch (independent work, fills scan's idle issue slots) ----
        // bf16-only table: lo-residual dropped; errors RMS-cancel over 475 taps
        // (~4e-4 max), proven invisible at the bf16 comparison floor in R4/R5.
        int idx = (blockIdx.x - SCAN_BLOCKS) * 256 + threadIdx.x;
        if (idx >= NEW_R * KP) return;
        int p = idx / KP, k = idx - p * KP;
        float v = 0.f;
        if (k < KW) {
            double t = (double)(k - WIDTH) * (158.4 / 441.0) - (double)p * 0.99;
            t = fmin(6.0, fmax(-6.0, t));
            float wc = __builtin_amdgcn_cosf((float)(t * (1.0 / 24.0)));
            double n = rint(t);
            float r2 = (float)((t - n) * 0.5);
            float sp = __builtin_amdgcn_sinf(r2 - floorf(r2));
            if (((long long)n) & 1) sp = -sp;
            float tp = (float)(t * M_PI);
            float snc = (t == 0.0) ? 1.f : sp / tp;
            v = snc * wc * wc * 0.3591836734693878f;
        }
        kth[fragB(p, k)] = f2bf(v);
        return;
    }

    // ---- scan branch: fused bandpass -> clip -> cos mix -> lowpass -> clip (f32) ----
    int id = blockIdx.x * 256 + threadIdx.x;
    if (id >= NSEQ * NCHUNK) return;
    int seq   = id / NCHUNK;
    int chunk = id - seq * NCHUNK;
    int band  = seq / BATCH;
    int batch = seq - band * BATCH;

    float b0f = (band == 0) ? P.b0[0] : (band == 1) ? P.b0[1] : P.b0[2];
    float a1f = (band == 0) ? P.a1[0] : (band == 1) ? P.a1[1] : P.a1[2];
    float a2f = (band == 0) ? P.a2[0] : (band == 1) ? P.a2[1] : P.a2[2];
    float wf  = (band == 0) ? P.w[0]  : (band == 1) ? P.w[1]  : P.w[2];
    float b2f = -b0f;
    float lb0 = P.lb0, lb1 = P.lb1, lb2 = P.lb2, la1 = P.la1, la2 = P.la2;

    const float*     xr   = x + batch * T_IN;
    unsigned short*  orow = xlp + seq * T_IN;
    const float4*    xr4  = (const float4*)xr;

    int t0 = chunk * LCHUNK;
    int s0 = t0 - WARM; if (s0 < 0) s0 = 0;
    int e  = t0 + LCHUNK;
    int nq = (e - s0) >> 2;           // 72 (chunk 0: 42)

    float bx1 = 0.f, bx2 = 0.f, by1 = 0.f, by2 = 0.f;
    float mx1 = 0.f, mx2 = 0.f, mz1 = 0.f, mz2 = 0.f;

    const float invsr  = 1.0f / 44100.0f;
    const float INV2PI = 0.15915494309189535f;
    const float PI2_A  = 6.28318548202514648f;
    const float PI2_B  = -1.7484556000744487e-7f;

    const float4 zero = make_float4(0.f, 0.f, 0.f, 0.f);
    const float4* pp = xr4 + (s0 >> 2);
    float4 c0 = pp[0];
    float4 c1 = (1 < nq) ? pp[1] : zero;
    float4 c2 = (2 < nq) ? pp[2] : zero;
    float4 c3 = (3 < nq) ? pp[3] : zero;

    for (int iq = 0; iq < nq; iq += 4) {
        float4 n0 = (iq + 4 < nq) ? pp[iq + 4] : zero;
        float4 n1 = (iq + 5 < nq) ? pp[iq + 5] : zero;
        float4 n2 = (iq + 6 < nq) ? pp[iq + 6] : zero;
        float4 n3 = (iq + 7 < nq) ? pp[iq + 7] : zero;

        // clamp via v_med3_f32 (1 instr vs min+max); identical for finite args,
        // and y/z are provably finite (bounded recursion, finite coeffs).
#define STEP(XT, TI, OUT) {                                                   \
        float y  = b0f*(XT) + b2f*bx2 - a1f*by1 - a2f*by2;                    \
        bx2 = bx1; bx1 = (XT); by2 = by1; by1 = y;                            \
        float cy = __builtin_amdgcn_fmed3f(y, -1.f, 1.f);                     \
        float tf = (float)(TI) * invsr;                                       \
        float X  = wf * tf;                                                   \
        float kk = __builtin_rintf(X * INV2PI);                               \
        float r  = fmaf(-kk, PI2_A, X);                                       \
        r        = fmaf(-kk, PI2_B, r);                                       \
        float cv = __builtin_amdgcn_cosf(r * INV2PI);                         \
        float m  = cy * cv;                                                   \
        float z  = lb0*m + lb1*mx1 + lb2*mx2 - la1*mz1 - la2*mz2;             \
        mx2 = mx1; mx1 = m; mz2 = mz1; mz1 = z;                               \
        OUT = __builtin_amdgcn_fmed3f(z, -1.f, 1.f); }

        // BOTH bounds required: chunk 0 has nq=42 (not %4), so iq=40 runs quad
        // indices 42,43 -> s >= e. Dropping `s < e` raced into chunk 1's output
        // (R2/R3 failure, absmax 0.58). Keep `s < e` FOREVER.
        // Store = packed bf16 (hw RNE cvt_pk, validated R5): uint2 at 2*s bytes,
        // s%4==0 -> 8B-aligned.
#define QUAD(CV, QI) {                                                        \
        int s = s0 + ((iq + QI) << 2);                                        \
        float o0, o1, o2, o3;                                                 \
        STEP(CV.x, s,     o0)                                                 \
        STEP(CV.y, s + 1, o1)                                                 \
        STEP(CV.z, s + 2, o2)                                                 \
        STEP(CV.w, s + 3, o3)                                                 \
        if (s >= t0 && s < e) {                                               \
            unsigned plo, phi;                                                \
            asm("v_cvt_pk_bf16_f32 %0, %1, %2" : "=v"(plo) : "v"(o0), "v"(o1)); \
            asm("v_cvt_pk_bf16_f32 %0, %1, %2" : "=v"(phi) : "v"(o2), "v"(o3)); \
            *(uint2*)&orow[s] = make_uint2(plo, phi);                         \
        } }

        QUAD(c0, 0)
        QUAD(c1, 1)
        QUAD(c2, 2)
        QUAD(c3, 3)
#undef QUAD
#undef STEP
        c0 = n0; c1 = n1; c2 = n2; c3 = n3;
    }
}

// ---------------- MFMA resample: out[f,p] = sum_k x[f*441+k-17] * kt[k][p] ----------------
// Single-pass bf16 GEMM (A and B both bf16-RNE; residual errors RMS-cancel, see above).
// F=48 frames/block, 3 blocks/CU (46,080 B static LDS), grid 504 = balanced 2-round.
// xlp is ALREADY bf16 (scan-side cvt) -> staging is pure bit movement: 4 ushort loads
// + 2 packs per group, half the read bytes of R5, L2-resident (21 MB < 32 MB agg L2).
#define MT3   21      // 21 blocks per sequence x 48 frames = 1008 >= 1000

__global__ __launch_bounds__(320) void resample_mfma(const unsigned short* __restrict__ xlp,
                                                     const unsigned short* __restrict__ kth,
                                                     float* __restrict__ out) {
    __shared__ unsigned short Ah[3][7680];   // 46,080 B static -> 3 blocks/CU

    int bid = blockIdx.x;
    int seq = bid / MT3;
    int mt  = bid - seq * MT3;
    int band  = seq / BATCH;
    int batch = seq - band * BATCH;
    int f0 = mt * 48;
    const unsigned short* xr = xlp + seq * T_IN;

    // stage 48 frame-windows (bf16 bits), frag-major with XOR-ks bank swizzle
    for (int i = threadIdx.x; i < 48 * 120; i += 320) {
        int r  = i / 120;                 // frame row 0..47
        int q  = i - r * 120;
        int c  = q * 4;                   // tap col base (0..476)
        int fr = f0 + r;
        int base = fr * ORIG_R - WIDTH + c;
        unsigned h0 = (base     >= 0 && base     < T_IN) ? xr[base]     : 0;
        unsigned h1 = (base + 1 >= 0 && base + 1 < T_IN) ? xr[base + 1] : 0;
        unsigned h2 = (base + 2 >= 0 && base + 2 < T_IN) ? xr[base + 2] : 0;
        unsigned h3 = (base + 3 >= 0 && base + 3 < T_IN) ? xr[base + 3] : 0;
        unsigned p01 = h0 | (h1 << 16);
        unsigned p23 = h2 | (h3 << 16);
        int tile = r >> 4, m = r & 15;
        int ks = c >> 5, qd = (c >> 3) & 3, j0 = c & 7;   // j0 in {0,4}
        int slot = (qd * 16 + m) ^ ks;                    // XOR swizzle (bijective per ks)
        int off = ks * 512 + slot * 8 + j0;               // 8B-aligned
        *(uint2*)&Ah[tile][off] = make_uint2(p01, p23);
    }
    __syncthreads();

    int w    = threadIdx.x >> 6;      // 0..4 -> phases p0 = w*32
    int lane = threadIdx.x & 63;
    int l15  = lane & 15;
    int quad = lane >> 4;

    floatx4 acc00 = {0,0,0,0}, acc01 = {0,0,0,0};   // [tile][half]
    floatx4 acc10 = {0,0,0,0}, acc11 = {0,0,0,0};
    floatx4 acc20 = {0,0,0,0}, acc21 = {0,0,0,0};

    const unsigned short* b0h = kth + (w * 2    ) * 7680 + lane * 8;  // pblk = w*2
    const unsigned short* b1h = kth + (w * 2 + 1) * 7680 + lane * 8;  // pblk = w*2+1

#pragma unroll
    for (int ks = 0; ks < 15; ++ks) {
        int o  = ks * 512;
        int sl = o + ((lane ^ ks) << 3);  // de-swizzled A slot: contiguous 1KB per wave
        short8 kh0 = *(const short8*)(b0h + o);
        short8 kh1 = *(const short8*)(b1h + o);
        short8 ah0 = *(const short8*)(&Ah[0][sl]);
        short8 ah1 = *(const short8*)(&Ah[1][sl]);
        short8 ah2 = *(const short8*)(&Ah[2][sl]);

        acc00 = __builtin_amdgcn_mfma_f32_16x16x32_bf16(ah0, kh0, acc00, 0, 0, 0);
        acc01 = __builtin_amdgcn_mfma_f32_16x16x32_bf16(ah0, kh1, acc01, 0, 0, 0);
        acc10 = __builtin_amdgcn_mfma_f32_16x16x32_bf16(ah1, kh0, acc10, 0, 0, 0);
        acc11 = __builtin_amdgcn_mfma_f32_16x16x32_bf16(ah1, kh1, acc11, 0, 0, 0);
        acc20 = __builtin_amdgcn_mfma_f32_16x16x32_bf16(ah2, kh0, acc20, 0, 0, 0);
        acc21 = __builtin_amdgcn_mfma_f32_16x16x32_bf16(ah2, kh1, acc21, 0, 0, 0);
    }

    // C/D layout: n = lane&15 (phase), m = quad*4 + reg (frame) -- verified R7
    int obase = (batch * NB + band) * TB_OUT;
    int p0 = w * 32;
#pragma unroll
    for (int r = 0; r < 4; ++r) {
        int fr0 = f0 + quad * 4 + r;
        int fr1 = fr0 + 16;
        int fr2 = fr0 + 32;
        if (fr0 < NFRAMES) {
            out[obase + fr0 * NEW_R + p0 + l15]      = acc00[r];
            out[obase + fr0 * NEW_R + p0 + 16 + l15] = acc01[r];
        }
        if (fr1 < NFRAMES) {
            out[obase + fr1 * NEW_R + p0 + l15]      = acc10[r];
            out[obase + fr1 * NEW_R + p0 + 16 + l15] = acc11[r];
        }
        if (fr2 < NFRAMES) {
            out[obase + fr2 * NEW_R + p0 + l15]      = acc20[r];
            out[obase + fr2 * NEW_R + p0 + 16 + l15] = acc21[r];
        }
    }
}

// ---------------- host ----------------
extern "C" void kernel_launch(void* const* d_in, const int* in_sizes, int n_in,
                              void* d_out, int out_size, void* d_ws, size_t ws_size,
                              hipStream_t stream) {
    const float*    x   = (const float*)d_in[0];
    float*          out = (float*)d_out;
    unsigned short* kth = (unsigned short*)((char*)d_ws + KTH_OFF);
    unsigned short* xlp = (unsigned short*)((char*)d_ws + XLP_OFF);

    ScanParams P;
    const double centers[NB] = {4000.0, 12000.0, 19025.0};
    const double Qs[NB]      = {0.5, 1.5, 19025.0 / 6050.0};
    for (int b = 0; b < NB; ++b) {
        double c  = centers[b], Q = Qs[b];
        double w0 = 2.0 * M_PI * c / 44100.0;
        double al = sin(w0) / (2.0 * Q);
        double a0 = 1.0 + al;
        P.b0[b] = (float)(al / a0);
        P.a1[b] = (float)(-2.0 * cos(w0) / a0);
        P.a2[b] = (float)((1.0 - al) / a0);
        P.w[b]  = 6.283185307179586f * (float)c;   // fl32(fl32(2pi)*c), validated
    }
    {
        double cut = 0.45 * 16000.0;
        double Q   = 0.7071067811865476;
        double w0  = 2.0 * M_PI * cut / 44100.0;
        double al  = sin(w0) / (2.0 * Q);
        double cs  = cos(w0);
        double a0  = 1.0 + al;
        P.lb0 = (float)(((1.0 - cs) / 2.0) / a0);
        P.lb1 = (float)((1.0 - cs) / a0);
        P.lb2 = P.lb0;
        P.la1 = (float)(-2.0 * cs / a0);
        P.la2 = (float)((1.0 - al) / a0);
    }

    // 1) fused IIR cascade -> xlp (bf16) AND frag-major bf16 sinc table (one launch;
    //    scan blocks first — the long pole — kt-init blocks backfill idle issue slots)
    scan_init_kernel<<<dim3(SCAN_BLOCKS + KT_BLOCKS), dim3(256), 0, stream>>>(
        x, xlp, kth, P);

    // 2) MFMA polyphase resample -> out (8 x 3 x 160000)
    resample_mfma<<<dim3(NSEQ * MT3), dim3(320), 0, stream>>>(xlp, kth, out);
}

// Round 7
// 107.782 us; speedup vs baseline: 1.0428x; 1.0428x over previous
//
#include <hip/hip_runtime.h>
#include <math.h>

// ---------------- problem constants ----------------
#define SRATE   44100
#define T_IN    441000
#define BATCH   8
#define NB      3
#define NSEQ    (NB*BATCH)        // 24
#define TB_OUT  160000
#define NEW_R   160
#define ORIG_R  441
#define KW      475               // sinc taps
#define KP      480               // K padded to 15*32 for MFMA
#define WIDTH   17
#define NFRAMES 1000

// IIR chunking: 441000 = 2625 * 168 ; warmup 96 (band-2 pole 0.9357 -> residual
// sigma ~ 2.9e-4, max over 10.6M samples ~ 1.6e-3 — below the 0.0039 bf16 floor;
// WARM=120 was sigma 6e-5, more margin than needed). 96 = 24 float4s keeps s0 aligned.
#define LCHUNK  168
#define NCHUNK  2625
#define WARM    96

// merged scan+init grid split: scan blocks first (long pole), kt-init blocks appended
#define SCAN_BLOCKS 247           // ceil(63000/256)
#define KT_BLOCKS   300           // 76800/256 exact

// workspace layout
#define KTH_OFF 0                 // frag-major bf16 table: 160*480 ushort = 153.6 KB
#define XLP_OFF (1u<<20)          // xlp f32: 24*441000*4 = 42.3 MB

typedef __attribute__((ext_vector_type(4))) float floatx4;
typedef __attribute__((ext_vector_type(8))) short short8;

// bf16 RNE (manual, used in kt-init where exact XLA-style RNE is cheap & off hot path)
__device__ inline unsigned short f2bf(float f) {
    union { float f; unsigned u; } v; v.f = f;
    unsigned u = v.u, r = (u >> 16) & 0xffffu, rem = u & 0xffffu;
    if (rem > 0x8000u || (rem == 0x8000u && (r & 1u))) r++;
    return (unsigned short)r;
}

// frag-major flat index for the GLOBAL B-table:
// element ktT[p][k] with p = pblk*16+n, k = ks*32 + qd*8 + j
// -> flat = pblk*7680 + ks*512 + (qd*16+n)*8 + j  (wave load = contiguous 1KB)
__device__ inline int fragB(int p, int k) {
    int pblk = p >> 4, n = p & 15;
    int ks = k >> 5, qd = (k >> 3) & 3, j = k & 7;
    return pblk * 7680 + ks * 512 + (qd * 16 + n) * 8 + j;
}

// ---------------- fused scan + sinc-table-init (merged launch) ----------------
// Heterodyne = XLA-f32 arithmetic (validated R5-R7 at bf16 floor) — numerics bit-identical.
// R6 lesson: scan is ISSUE-bound (0.96 waves/SIMD), not write-BW-bound — bf16-xlp
// halving bought nothing; keep f32 xlp (proven 109.7 structure).
struct ScanParams {
    float b0[NB], a1[NB], a2[NB], w[NB];
    float lb0, lb1, lb2, la1, la2;
};

__global__ __launch_bounds__(256) void scan_init_kernel(const float* __restrict__ x,
                                                        float* __restrict__ xlp,
                                                        unsigned short* __restrict__ kth,
                                                        ScanParams P) {
    if (blockIdx.x >= SCAN_BLOCKS) {
        // ---- kt_init branch (independent work, fills scan's idle issue slots) ----
        // bf16-only table: lo-residual dropped; errors RMS-cancel over 475 taps
        // (~4e-4 max), proven invisible at the bf16 comparison floor in R4/R5.
        int idx = (blockIdx.x - SCAN_BLOCKS) * 256 + threadIdx.x;
        if (idx >= NEW_R * KP) return;
        int p = idx / KP, k = idx - p * KP;
        float v = 0.f;
        if (k < KW) {
            double t = (double)(k - WIDTH) * (158.4 / 441.0) - (double)p * 0.99;
            t = fmin(6.0, fmax(-6.0, t));
            float wc = __builtin_amdgcn_cosf((float)(t * (1.0 / 24.0)));
            double n = rint(t);
            float r2 = (float)((t - n) * 0.5);
            float sp = __builtin_amdgcn_sinf(r2 - floorf(r2));
            if (((long long)n) & 1) sp = -sp;
            float tp = (float)(t * M_PI);
            float snc = (t == 0.0) ? 1.f : sp / tp;
            v = snc * wc * wc * 0.3591836734693878f;
        }
        kth[fragB(p, k)] = f2bf(v);
        return;
    }

    // ---- scan branch: fused bandpass -> clip -> cos mix -> lowpass -> clip (f32) ----
    int id = blockIdx.x * 256 + threadIdx.x;
    if (id >= NSEQ * NCHUNK) return;
    int seq   = id / NCHUNK;
    int chunk = id - seq * NCHUNK;
    int band  = seq / BATCH;
    int batch = seq - band * BATCH;

    float b0f = (band == 0) ? P.b0[0] : (band == 1) ? P.b0[1] : P.b0[2];
    float a1f = (band == 0) ? P.a1[0] : (band == 1) ? P.a1[1] : P.a1[2];
    float a2f = (band == 0) ? P.a2[0] : (band == 1) ? P.a2[1] : P.a2[2];
    float wf  = (band == 0) ? P.w[0]  : (band == 1) ? P.w[1]  : P.w[2];
    float b2f = -b0f;
    float lb0 = P.lb0, lb1 = P.lb1, lb2 = P.lb2, la1 = P.la1, la2 = P.la2;

    const float*  xr   = x + batch * T_IN;
    float*        orow = xlp + seq * T_IN;
    const float4* xr4  = (const float4*)xr;

    int t0 = chunk * LCHUNK;
    int s0 = t0 - WARM; if (s0 < 0) s0 = 0;
    int e  = t0 + LCHUNK;
    int nq = (e - s0) >> 2;           // 66 (chunk 0: 42)

    float bx1 = 0.f, bx2 = 0.f, by1 = 0.f, by2 = 0.f;
    float mx1 = 0.f, mx2 = 0.f, mz1 = 0.f, mz2 = 0.f;

    const float invsr  = 1.0f / 44100.0f;
    const float INV2PI = 0.15915494309189535f;
    const float PI2_A  = 6.28318548202514648f;
    const float PI2_B  = -1.7484556000744487e-7f;

    const float4 zero = make_float4(0.f, 0.f, 0.f, 0.f);
    const float4* pp = xr4 + (s0 >> 2);
    float4 c0 = pp[0];
    float4 c1 = (1 < nq) ? pp[1] : zero;
    float4 c2 = (2 < nq) ? pp[2] : zero;
    float4 c3 = (3 < nq) ? pp[3] : zero;

    for (int iq = 0; iq < nq; iq += 4) {
        float4 n0 = (iq + 4 < nq) ? pp[iq + 4] : zero;
        float4 n1 = (iq + 5 < nq) ? pp[iq + 5] : zero;
        float4 n2 = (iq + 6 < nq) ? pp[iq + 6] : zero;
        float4 n3 = (iq + 7 < nq) ? pp[iq + 7] : zero;

        // clamp via v_med3_f32 (1 instr vs min+max); identical for finite args,
        // and y/z are provably finite (bounded recursion, finite coeffs).
#define STEP(XT, TI, OUT) {                                                   \
        float y  = b0f*(XT) + b2f*bx2 - a1f*by1 - a2f*by2;                    \
        bx2 = bx1; bx1 = (XT); by2 = by1; by1 = y;                            \
        float cy = __builtin_amdgcn_fmed3f(y, -1.f, 1.f);                     \
        float tf = (float)(TI) * invsr;                                       \
        float X  = wf * tf;                                                   \
        float kk = __builtin_rintf(X * INV2PI);                               \
        float r  = fmaf(-kk, PI2_A, X);                                       \
        r        = fmaf(-kk, PI2_B, r);                                       \
        float cv = __builtin_amdgcn_cosf(r * INV2PI);                         \
        float m  = cy * cv;                                                   \
        float z  = lb0*m + lb1*mx1 + lb2*mx2 - la1*mz1 - la2*mz2;             \
        mx2 = mx1; mx1 = m; mz2 = mz1; mz1 = z;                               \
        OUT = __builtin_amdgcn_fmed3f(z, -1.f, 1.f); }

        // BOTH bounds required: chunk 0 has nq=42 (not %4), so iq=40 runs quad
        // indices 42,43 -> s >= e. Dropping `s < e` raced into chunk 1's output
        // (R2/R3 failure, absmax 0.58). Keep `s < e` FOREVER.
#define QUAD(CV, QI) {                                                        \
        int s = s0 + ((iq + QI) << 2);                                        \
        float o0, o1, o2, o3;                                                 \
        STEP(CV.x, s,     o0)                                                 \
        STEP(CV.y, s + 1, o1)                                                 \
        STEP(CV.z, s + 2, o2)                                                 \
        STEP(CV.w, s + 3, o3)                                                 \
        if (s >= t0 && s < e)                                                 \
            ((float4*)orow)[s >> 2] = make_float4(o0, o1, o2, o3); }

        QUAD(c0, 0)
        QUAD(c1, 1)
        QUAD(c2, 2)
        QUAD(c3, 3)
#undef QUAD
#undef STEP
        c0 = n0; c1 = n1; c2 = n2; c3 = n3;
    }
}

// ---------------- MFMA resample: out[f,p] = sum_k x[f*441+k-17] * kt[k][p] ----------------
// Single-pass bf16 GEMM (A and B both bf16-RNE; residual errors RMS-cancel, see above).
// F=48 frames/block, 3 blocks/CU (46,080 B static LDS), grid 504 = balanced 2-round.
// B-table L2 re-read 504 x 154KB = 78 MB. 6 MFMA + 5 loads/ks.
// A staged frag-major with XOR-ks swizzle (write conflicts 16->4-way, reads contiguous);
// staging uses hardware v_cvt_pk_bf16_f32 (validated R5: matches manual RNE bit-exactly).
#define MT3   21      // 21 blocks per sequence x 48 frames = 1008 >= 1000

__global__ __launch_bounds__(320) void resample_mfma(const float* __restrict__ xlp,
                                                     const unsigned short* __restrict__ kth,
                                                     float* __restrict__ out) {
    __shared__ unsigned short Ah[3][7680];   // 46,080 B static -> 3 blocks/CU

    int bid = blockIdx.x;
    int seq = bid / MT3;
    int mt  = bid - seq * MT3;
    int band  = seq / BATCH;
    int batch = seq - band * BATCH;
    int f0 = mt * 48;
    const float* xr = xlp + seq * T_IN;

    // stage 48 frame-windows -> bf16 (hw RNE), frag-major with XOR-ks bank swizzle
    for (int i = threadIdx.x; i < 48 * 120; i += 320) {
        int r  = i / 120;                 // frame row 0..47
        int q  = i - r * 120;
        int c  = q * 4;                   // tap col base (0..476)
        int fr = f0 + r;
        int base = fr * ORIG_R - WIDTH + c;
        float v0 = (base     >= 0 && base     < T_IN) ? xr[base]     : 0.f;
        float v1 = (base + 1 >= 0 && base + 1 < T_IN) ? xr[base + 1] : 0.f;
        float v2 = (base + 2 >= 0 && base + 2 < T_IN) ? xr[base + 2] : 0.f;
        float v3 = (base + 3 >= 0 && base + 3 < T_IN) ? xr[base + 3] : 0.f;
        unsigned p01, p23;  // {lo=bf16(v0), hi=bf16(v1)} — same layout as short4{h0..h3}
        asm("v_cvt_pk_bf16_f32 %0, %1, %2" : "=v"(p01) : "v"(v0), "v"(v1));
        asm("v_cvt_pk_bf16_f32 %0, %1, %2" : "=v"(p23) : "v"(v2), "v"(v3));
        int tile = r >> 4, m = r & 15;
        int ks = c >> 5, qd = (c >> 3) & 3, j0 = c & 7;   // j0 in {0,4}
        int slot = (qd * 16 + m) ^ ks;                    // XOR swizzle (bijective per ks)
        int off = ks * 512 + slot * 8 + j0;               // 8B-aligned
        *(uint2*)&Ah[tile][off] = make_uint2(p01, p23);
    }
    __syncthreads();

    int w    = threadIdx.x >> 6;      // 0..4 -> phases p0 = w*32
    int lane = threadIdx.x & 63;
    int l15  = lane & 15;
    int quad = lane >> 4;

    floatx4 acc00 = {0,0,0,0}, acc01 = {0,0,0,0};   // [tile][half]
    floatx4 acc10 = {0,0,0,0}, acc11 = {0,0,0,0};
    floatx4 acc20 = {0,0,0,0}, acc21 = {0,0,0,0};

    const unsigned short* b0h = kth + (w * 2    ) * 7680 + lane * 8;  // pblk = w*2
    const unsigned short* b1h = kth + (w * 2 + 1) * 7680 + lane * 8;  // pblk = w*2+1

#pragma unroll
    for (int ks = 0; ks < 15; ++ks) {
        int o  = ks * 512;
        int sl = o + ((lane ^ ks) << 3);  // de-swizzled A slot: contiguous 1KB per wave
        short8 kh0 = *(const short8*)(b0h + o);
        short8 kh1 = *(const short8*)(b1h + o);
        short8 ah0 = *(const short8*)(&Ah[0][sl]);
        short8 ah1 = *(const short8*)(&Ah[1][sl]);
        short8 ah2 = *(const short8*)(&Ah[2][sl]);

        acc00 = __builtin_amdgcn_mfma_f32_16x16x32_bf16(ah0, kh0, acc00, 0, 0, 0);
        acc01 = __builtin_amdgcn_mfma_f32_16x16x32_bf16(ah0, kh1, acc01, 0, 0, 0);
        acc10 = __builtin_amdgcn_mfma_f32_16x16x32_bf16(ah1, kh0, acc10, 0, 0, 0);
        acc11 = __builtin_amdgcn_mfma_f32_16x16x32_bf16(ah1, kh1, acc11, 0, 0, 0);
        acc20 = __builtin_amdgcn_mfma_f32_16x16x32_bf16(ah2, kh0, acc20, 0, 0, 0);
        acc21 = __builtin_amdgcn_mfma_f32_16x16x32_bf16(ah2, kh1, acc21, 0, 0, 0);
    }

    // C/D layout: n = lane&15 (phase), m = quad*4 + reg (frame) -- verified R7
    int obase = (batch * NB + band) * TB_OUT;
    int p0 = w * 32;
#pragma unroll
    for (int r = 0; r < 4; ++r) {
        int fr0 = f0 + quad * 4 + r;
        int fr1 = fr0 + 16;
        int fr2 = fr0 + 32;
        if (fr0 < NFRAMES) {
            out[obase + fr0 * NEW_R + p0 + l15]      = acc00[r];
            out[obase + fr0 * NEW_R + p0 + 16 + l15] = acc01[r];
        }
        if (fr1 < NFRAMES) {
            out[obase + fr1 * NEW_R + p0 + l15]      = acc10[r];
            out[obase + fr1 * NEW_R + p0 + 16 + l15] = acc11[r];
        }
        if (fr2 < NFRAMES) {
            out[obase + fr2 * NEW_R + p0 + l15]      = acc20[r];
            out[obase + fr2 * NEW_R + p0 + 16 + l15] = acc21[r];
        }
    }
}

// ---------------- host ----------------
extern "C" void kernel_launch(void* const* d_in, const int* in_sizes, int n_in,
                              void* d_out, int out_size, void* d_ws, size_t ws_size,
                              hipStream_t stream) {
    const float*    x   = (const float*)d_in[0];
    float*          out = (float*)d_out;
    unsigned short* kth = (unsigned short*)((char*)d_ws + KTH_OFF);
    float*          xlp = (float*)((char*)d_ws + XLP_OFF);

    ScanParams P;
    const double centers[NB] = {4000.0, 12000.0, 19025.0};
    const double Qs[NB]      = {0.5, 1.5, 19025.0 / 6050.0};
    for (int b = 0; b < NB; ++b) {
        double c  = centers[b], Q = Qs[b];
        double w0 = 2.0 * M_PI * c / 44100.0;
        double al = sin(w0) / (2.0 * Q);
        double a0 = 1.0 + al;
        P.b0[b] = (float)(al / a0);
        P.a1[b] = (float)(-2.0 * cos(w0) / a0);
        P.a2[b] = (float)((1.0 - al) / a0);
        P.w[b]  = 6.283185307179586f * (float)c;   // fl32(fl32(2pi)*c), validated
    }
    {
        double cut = 0.45 * 16000.0;
        double Q   = 0.7071067811865476;
        double w0  = 2.0 * M_PI * cut / 44100.0;
        double al  = sin(w0) / (2.0 * Q);
        double cs  = cos(w0);
        double a0  = 1.0 + al;
        P.lb0 = (float)(((1.0 - cs) / 2.0) / a0);
        P.lb1 = (float)((1.0 - cs) / a0);
        P.lb2 = P.lb0;
        P.la1 = (float)(-2.0 * cs / a0);
        P.la2 = (float)((1.0 - al) / a0);
    }

    // 1) fused IIR cascade -> xlp AND frag-major bf16 sinc table (one launch;
    //    scan blocks first — the long pole — kt-init blocks backfill idle issue slots)
    scan_init_kernel<<<dim3(SCAN_BLOCKS + KT_BLOCKS), dim3(256), 0, stream>>>(
        x, xlp, kth, P);

    // 2) MFMA polyphase resample -> out (8 x 3 x 160000)
    resample_mfma<<<dim3(NSEQ * MT3), dim3(320), 0, stream>>>(xlp, kth, out);
}